// Round 2
// baseline (845.204 us; speedup 1.0000x reference)
//
#include <hip/hip_runtime.h>

#define N_NODES 50000
#define N_EDGES 800000
#define HDIM 128

typedef __bf16 bf16x8 __attribute__((ext_vector_type(8)));
typedef float f32x4 __attribute__((ext_vector_type(4)));

// round-to-nearest-even fp32 -> bf16
static __device__ __forceinline__ unsigned short f2bf(float f) {
    unsigned int u = __float_as_uint(f);
    u += 0x7fffu + ((u >> 16) & 1u);
    return (unsigned short)(u >> 16);
}

static __device__ __forceinline__ float silu_f(float x) {
    return x / (1.0f + __expf(-x));
}

// ---- convert weights to bf16, transposed: Wt[n][k] = W[k][n] ----
__global__ void conv_weights(const float* __restrict__ ew1, const float* __restrict__ ew2,
                             const float* __restrict__ nw1, const float* __restrict__ nw2,
                             unsigned short* __restrict__ W1t, unsigned short* __restrict__ W2t,
                             unsigned short* __restrict__ N1t, unsigned short* __restrict__ N2t) {
    int i = blockIdx.x * blockDim.x + threadIdx.x;
    if (i < 36864) {                       // 128*288
        int n = i / 288, k = i % 288;
        W1t[i] = (k < 265) ? f2bf(ew1[k * 128 + n]) : (unsigned short)0;
    } else if (i < 53248) {                // + 128*128
        int j = i - 36864;
        int n = j / 128, k = j % 128;
        W2t[j] = f2bf(ew2[k * 128 + n]);
    } else if (i < 86016) {                // + 128*256
        int j = i - 53248;
        int n = j / 256, k = j % 256;
        N1t[j] = f2bf(nw1[k * 128 + n]);
    } else if (i < 102400) {               // + 128*128
        int j = i - 86016;
        int n = j / 128, k = j % 128;
        N2t[j] = f2bf(nw2[k * 128 + n]);
    }
}

// ---- sort edges by source: histogram -> scan -> bucket scatter ----
__global__ void hist_kernel(const int* __restrict__ eidx, int* __restrict__ hist) {
    int e = blockIdx.x * blockDim.x + threadIdx.x;
    if (e < N_EDGES) atomicAdd(&hist[eidx[e]], 1);
}

__global__ __launch_bounds__(1024) void scan_kernel(const int* __restrict__ hist,
                                                    int* __restrict__ offsets) {
    __shared__ int part[1024];
    const int t = threadIdx.x;
    constexpr int C = (N_NODES + 1023) / 1024;   // 49
    const int base = t * C;
    int s = 0;
#pragma unroll 1
    for (int i = 0; i < C; ++i) {
        int idx = base + i;
        if (idx < N_NODES) s += hist[idx];
    }
    part[t] = s;
    __syncthreads();
    // inclusive Hillis-Steele scan over partials
    for (int off = 1; off < 1024; off <<= 1) {
        int tmp = (t >= off) ? part[t - off] : 0;
        __syncthreads();
        part[t] += tmp;
        __syncthreads();
    }
    int run = part[t] - s;   // exclusive base for this chunk
#pragma unroll 1
    for (int i = 0; i < C; ++i) {
        int idx = base + i;
        if (idx < N_NODES) {
            offsets[idx] = run;
            run += hist[idx];
        }
    }
}

__global__ void perm_kernel(const int* __restrict__ eidx, const int* __restrict__ offsets,
                            int* __restrict__ cursor, int* __restrict__ perm) {
    int e = blockIdx.x * blockDim.x + threadIdx.x;
    if (e < N_EDGES) {
        int src = eidx[e];
        int pos = offsets[src] + atomicAdd(&cursor[src], 1);
        perm[pos] = e;
    }
}

// ---- edge MLP + segmented scatter-add ----
// Processes 64 edges (in src-sorted perm order) per workgroup. Epilogue stages
// fp32 results in LDS and emits one atomicAdd per (src-run, col) segment
// (~5 distinct src per tile at avg degree 16 -> ~13x fewer atomics).
__global__ __launch_bounds__(256, 4) void edge_kernel(
    const float* __restrict__ nf, const float* __restrict__ lattices,
    const float* __restrict__ frac_diff, const int* __restrict__ eidx,
    const int* __restrict__ e2g, const int* __restrict__ perm,
    const unsigned short* __restrict__ W1t, const float* __restrict__ b1,
    const unsigned short* __restrict__ W2t, const float* __restrict__ b2,
    float* __restrict__ agg) {
    constexpr int SA = 296;   // A row stride (bf16 elems)
    constexpr int S2 = 136;   // e-buffer row stride (bf16 elems)
    constexpr int SF = 132;   // fp32 staging row stride (floats)
    __shared__ unsigned short sm[64 * SA];   // 37888 B; reused as float[64][SF]
    __shared__ int ssrc[64];

    const int tid = threadIdx.x;
    const int e0 = blockIdx.x * 64;

    // ---- build A tile: [0,128)=h[src], [128,256)=h[dst], [256,262)=lat, [262,265)=fd
    {
        const int m = tid >> 2;
        const int q = tid & 3;
        const int e = perm[e0 + m];
        const int src = eidx[e];
        const int dst = eidx[N_EDGES + e];
        unsigned short* row = sm + m * SA;
        const int cb = q * 32;
        const float4* hi4 = (const float4*)(nf + (size_t)src * HDIM) + q * 8;
        const float4* hj4 = (const float4*)(nf + (size_t)dst * HDIM) + q * 8;
#pragma unroll
        for (int j = 0; j < 8; ++j) {
            float4 v = hi4[j];
            *(ushort4*)(row + cb + 4 * j) =
                make_ushort4(f2bf(v.x), f2bf(v.y), f2bf(v.z), f2bf(v.w));
            float4 w = hj4[j];
            *(ushort4*)(row + HDIM + cb + 4 * j) =
                make_ushort4(f2bf(w.x), f2bf(w.y), f2bf(w.z), f2bf(w.w));
        }
        if (q == 0) {
            ssrc[m] = src;
            const int g = e2g[e];
#pragma unroll
            for (int j = 0; j < 6; ++j) row[256 + j] = f2bf(lattices[g * 6 + j]);
#pragma unroll
            for (int j = 0; j < 3; ++j) row[262 + j] = f2bf(frac_diff[e * 3 + j]);
#pragma unroll
            for (int j = 265; j < 288; ++j) row[j] = 0;
        }
    }
    __syncthreads();

    const int wave = tid >> 6;
    const int lane = tid & 63;
    const int lr = lane & 15;
    const int kq = lane >> 4;

    // ---- layer 1 (K=288)
    f32x4 acc[8] = {};
    const int arow = (wave * 16 + lr) * SA;
#pragma unroll
    for (int ks = 0; ks < 288; ks += 32) {
        bf16x8 a = *(const bf16x8*)(sm + arow + ks + kq * 8);
#pragma unroll
        for (int nt = 0; nt < 8; ++nt) {
            bf16x8 bb = *(const bf16x8*)(W1t + (nt * 16 + lr) * 288 + ks + kq * 8);
            acc[nt] = __builtin_amdgcn_mfma_f32_16x16x32_bf16(a, bb, acc[nt], 0, 0, 0);
        }
    }
    __syncthreads();

    // ---- silu + bias -> LDS bf16 e-buffer
#pragma unroll
    for (int nt = 0; nt < 8; ++nt) {
        const int col = nt * 16 + lr;
        const float bias = b1[col];
#pragma unroll
        for (int r = 0; r < 4; ++r) {
            const int m = wave * 16 + kq * 4 + r;
            sm[m * S2 + col] = f2bf(silu_f(acc[nt][r] + bias));
        }
    }
    __syncthreads();

    // ---- layer 2 (K=128)
    f32x4 acc2[8] = {};
    const int arow2 = (wave * 16 + lr) * S2;
#pragma unroll
    for (int ks = 0; ks < 128; ks += 32) {
        bf16x8 a = *(const bf16x8*)(sm + arow2 + ks + kq * 8);
#pragma unroll
        for (int nt = 0; nt < 8; ++nt) {
            bf16x8 bb = *(const bf16x8*)(W2t + (nt * 16 + lr) * 128 + ks + kq * 8);
            acc2[nt] = __builtin_amdgcn_mfma_f32_16x16x32_bf16(a, bb, acc2[nt], 0, 0, 0);
        }
    }
    __syncthreads();   // all reads of e-buffer done before fp32 overwrite

    // ---- stage silu(layer2) fp32 in LDS
    float* smf = (float*)sm;
#pragma unroll
    for (int nt = 0; nt < 8; ++nt) {
        const int col = nt * 16 + lr;
        const float bias = b2[col];
#pragma unroll
        for (int r = 0; r < 4; ++r) {
            const int m = wave * 16 + kq * 4 + r;
            smf[m * SF + col] = silu_f(acc2[nt][r] + bias);
        }
    }
    __syncthreads();

    // ---- segmented reduction: thread = (col, half); walk 32 sorted rows
    {
        const int col = tid >> 1;
        const int r0 = (tid & 1) * 32;
        float sum = 0.0f;
        int cur = ssrc[r0];
#pragma unroll 1
        for (int r = r0; r < r0 + 32; ++r) {
            int s = ssrc[r];
            float v = smf[r * SF + col];
            if (s != cur) {
                atomicAdd(&agg[(size_t)cur * HDIM + col], sum);
                sum = 0.0f;
                cur = s;
            }
            sum += v;
        }
        atomicAdd(&agg[(size_t)cur * HDIM + col], sum);
    }
}

// ---- node MLP: h = concat(nf, agg/cnt) -> silu(h@N1+b1) -> silu(@N2+b2) + nf
__global__ __launch_bounds__(256, 4) void node_kernel(
    const float* __restrict__ nf, const float* __restrict__ agg,
    const int* __restrict__ cnt,
    const unsigned short* __restrict__ N1t, const float* __restrict__ b1,
    const unsigned short* __restrict__ N2t, const float* __restrict__ b2,
    float* __restrict__ out) {
    constexpr int SA = 264;
    constexpr int S2 = 136;
    __shared__ unsigned short sm[64 * SA];

    const int tid = threadIdx.x;
    const int n0 = blockIdx.x * 64;

    {
        const int m = tid >> 2;
        const int q = tid & 3;
        const int node = n0 + m;
        unsigned short* row = sm + m * SA;
        const int cb = q * 32;
        if (node < N_NODES) {
            const float inv = 1.0f / (float)max(cnt[node], 1);
            const float4* a4 = (const float4*)(nf + (size_t)node * HDIM) + q * 8;
            const float4* g4 = (const float4*)(agg + (size_t)node * HDIM) + q * 8;
#pragma unroll
            for (int j = 0; j < 8; ++j) {
                float4 v = a4[j];
                *(ushort4*)(row + cb + 4 * j) =
                    make_ushort4(f2bf(v.x), f2bf(v.y), f2bf(v.z), f2bf(v.w));
                float4 g = g4[j];
                *(ushort4*)(row + HDIM + cb + 4 * j) =
                    make_ushort4(f2bf(g.x * inv), f2bf(g.y * inv), f2bf(g.z * inv), f2bf(g.w * inv));
            }
        } else {
#pragma unroll
            for (int j = 0; j < 8; ++j) {
                *(ushort4*)(row + cb + 4 * j) = make_ushort4(0, 0, 0, 0);
                *(ushort4*)(row + HDIM + cb + 4 * j) = make_ushort4(0, 0, 0, 0);
            }
        }
    }
    __syncthreads();

    const int wave = tid >> 6;
    const int lane = tid & 63;
    const int lr = lane & 15;
    const int kq = lane >> 4;

    f32x4 acc[8] = {};
    const int arow = (wave * 16 + lr) * SA;
#pragma unroll
    for (int ks = 0; ks < 256; ks += 32) {
        bf16x8 a = *(const bf16x8*)(sm + arow + ks + kq * 8);
#pragma unroll
        for (int nt = 0; nt < 8; ++nt) {
            bf16x8 bb = *(const bf16x8*)(N1t + (nt * 16 + lr) * 256 + ks + kq * 8);
            acc[nt] = __builtin_amdgcn_mfma_f32_16x16x32_bf16(a, bb, acc[nt], 0, 0, 0);
        }
    }
    __syncthreads();

#pragma unroll
    for (int nt = 0; nt < 8; ++nt) {
        const int col = nt * 16 + lr;
        const float bias = b1[col];
#pragma unroll
        for (int r = 0; r < 4; ++r) {
            const int m = wave * 16 + kq * 4 + r;
            sm[m * S2 + col] = f2bf(silu_f(acc[nt][r] + bias));
        }
    }
    __syncthreads();

    f32x4 acc2[8] = {};
    const int arow2 = (wave * 16 + lr) * S2;
#pragma unroll
    for (int ks = 0; ks < 128; ks += 32) {
        bf16x8 a = *(const bf16x8*)(sm + arow2 + ks + kq * 8);
#pragma unroll
        for (int nt = 0; nt < 8; ++nt) {
            bf16x8 bb = *(const bf16x8*)(N2t + (nt * 16 + lr) * 128 + ks + kq * 8);
            acc2[nt] = __builtin_amdgcn_mfma_f32_16x16x32_bf16(a, bb, acc2[nt], 0, 0, 0);
        }
    }

#pragma unroll
    for (int nt = 0; nt < 8; ++nt) {
        const int col = nt * 16 + lr;
        const float bias = b2[col];
#pragma unroll
        for (int r = 0; r < 4; ++r) {
            const int node = n0 + wave * 16 + kq * 4 + r;
            if (node < N_NODES) {
                const size_t o = (size_t)node * HDIM + col;
                out[o] = nf[o] + silu_f(acc2[nt][r] + bias);
            }
        }
    }
}

extern "C" void kernel_launch(void* const* d_in, const int* in_sizes, int n_in,
                              void* d_out, int out_size, void* d_ws, size_t ws_size,
                              hipStream_t stream) {
    const float* node_features = (const float*)d_in[0];
    const float* lattices = (const float*)d_in[2];
    const float* frac_diff = (const float*)d_in[3];
    const int* edge_index = (const int*)d_in[4];
    const int* edge2graph = (const int*)d_in[5];
    const float* e_w1 = (const float*)d_in[6];
    const float* e_b1 = (const float*)d_in[7];
    const float* e_w2 = (const float*)d_in[8];
    const float* e_b2 = (const float*)d_in[9];
    const float* n_w1 = (const float*)d_in[10];
    const float* n_b1 = (const float*)d_in[11];
    const float* n_w2 = (const float*)d_in[12];
    const float* n_b2 = (const float*)d_in[13];

    // workspace layout (bytes):
    //   [0, 204800)                weights bf16 (W1t, W2t, N1t, N2t)
    //   [204800, +25.6MB)          agg   N*128 fp32          } zeroed together
    //   [.., +200K)                hist  N int               }
    //   [.., +200K)                cursor N int              }
    //   [.., +200K)                offsets N int
    //   [.., +3.2MB)               perm  E int
    char* ws = (char*)d_ws;
    unsigned short* W1t = (unsigned short*)(ws);
    unsigned short* W2t = (unsigned short*)(ws + 73728);
    unsigned short* N1t = (unsigned short*)(ws + 106496);
    unsigned short* N2t = (unsigned short*)(ws + 172032);
    size_t off = 204800;
    float* agg = (float*)(ws + off);       off += (size_t)N_NODES * HDIM * 4;
    int* hist = (int*)(ws + off);          off += (size_t)N_NODES * 4;
    int* cursor = (int*)(ws + off);        off += (size_t)N_NODES * 4;
    size_t zero_end = off;
    int* offsets = (int*)(ws + off);       off += (size_t)N_NODES * 4;
    int* perm = (int*)(ws + off);          off += (size_t)N_EDGES * 4;

    // zero agg + hist + cursor in one shot (ws is re-poisoned each launch)
    hipMemsetAsync(ws + 204800, 0, zero_end - 204800, stream);

    conv_weights<<<400, 256, 0, stream>>>(e_w1, e_w2, n_w1, n_w2, W1t, W2t, N1t, N2t);

    hist_kernel<<<(N_EDGES + 255) / 256, 256, 0, stream>>>(edge_index, hist);
    scan_kernel<<<1, 1024, 0, stream>>>(hist, offsets);
    perm_kernel<<<(N_EDGES + 255) / 256, 256, 0, stream>>>(edge_index, offsets, cursor, perm);

    edge_kernel<<<N_EDGES / 64, 256, 0, stream>>>(
        node_features, lattices, frac_diff, edge_index, edge2graph, perm,
        W1t, e_b1, W2t, e_b2, agg);

    node_kernel<<<(N_NODES + 63) / 64, 256, 0, stream>>>(
        node_features, agg, hist, N1t, n_b1, N2t, n_b2, (float*)d_out);
}

// Round 3
// 644.255 us; speedup vs baseline: 1.3119x; 1.3119x over previous
//
#include <hip/hip_runtime.h>

#define N_NODES 50000
#define N_EDGES 800000
#define HDIM 128
#define N_GRAPH 2048

typedef __bf16 bf16x8 __attribute__((ext_vector_type(8)));
typedef float f32x4 __attribute__((ext_vector_type(4)));

// round-to-nearest-even fp32 -> bf16
static __device__ __forceinline__ unsigned short f2bf(float f) {
    unsigned int u = __float_as_uint(f);
    u += 0x7fffu + ((u >> 16) & 1u);
    return (unsigned short)(u >> 16);
}
static __device__ __forceinline__ float bflo(unsigned int u) { return __uint_as_float(u << 16); }
static __device__ __forceinline__ float bfhi(unsigned int u) { return __uint_as_float(u & 0xFFFF0000u); }

static __device__ __forceinline__ float silu_f(float x) {
    return x / (1.0f + __expf(-x));
}

// ---- one-shot prep: transposed bf16 weights + per-graph L = b1 + lat@W1c ----
// items: W1aT 16384 | W1bT 16384 | W2t 16384 | N1t 32768 | N2t 16384 | L 262144
__global__ void prep_kernel(const float* __restrict__ ew1, const float* __restrict__ ew2,
                            const float* __restrict__ nw1, const float* __restrict__ nw2,
                            const float* __restrict__ eb1, const float* __restrict__ lattices,
                            unsigned short* __restrict__ W1aT, unsigned short* __restrict__ W1bT,
                            unsigned short* __restrict__ W2t, unsigned short* __restrict__ N1t,
                            unsigned short* __restrict__ N2t, unsigned short* __restrict__ Lb) {
    int i = blockIdx.x * blockDim.x + threadIdx.x;
    if (i < 16384) {
        int n = i >> 7, k = i & 127;
        W1aT[i] = f2bf(ew1[k * 128 + n]);
    } else if (i < 32768) {
        int j = i - 16384; int n = j >> 7, k = j & 127;
        W1bT[j] = f2bf(ew1[(128 + k) * 128 + n]);
    } else if (i < 49152) {
        int j = i - 32768; int n = j >> 7, k = j & 127;
        W2t[j] = f2bf(ew2[k * 128 + n]);
    } else if (i < 81920) {
        int j = i - 49152; int n = j >> 8, k = j & 255;
        N1t[j] = f2bf(nw1[k * 128 + n]);
    } else if (i < 98304) {
        int j = i - 81920; int n = j >> 7, k = j & 127;
        N2t[j] = f2bf(nw2[k * 128 + n]);
    } else if (i < 98304 + 262144) {
        int j = i - 98304; int g = j >> 7, c = j & 127;
        float s = eb1[c];
#pragma unroll
        for (int t = 0; t < 6; ++t) s += lattices[g * 6 + t] * ew1[(256 + t) * 128 + c];
        Lb[j] = f2bf(s);
    }
}

// ---- sort by src: hist -> in-place scan -> bucket scatter (perm split u16/u8) ----
__global__ void hist_kernel(const int* __restrict__ eidx, int* __restrict__ buf) {
    int e = blockIdx.x * blockDim.x + threadIdx.x;
    if (e < N_EDGES) atomicAdd(&buf[eidx[e]], 1);
}

__global__ __launch_bounds__(1024) void scan_kernel(int* __restrict__ buf) {
    __shared__ int part[1024];
    constexpr int C = (N_NODES + 1023) / 1024;   // 49
    const int t = threadIdx.x;
    const int base = t * C;
    int vals[C];
    int s = 0;
#pragma unroll
    for (int i = 0; i < C; ++i) {
        int idx = base + i;
        vals[i] = (idx < N_NODES) ? buf[idx] : 0;
        s += vals[i];
    }
    part[t] = s;
    __syncthreads();
    for (int off = 1; off < 1024; off <<= 1) {
        int tmp = (t >= off) ? part[t - off] : 0;
        __syncthreads();
        part[t] += tmp;
        __syncthreads();
    }
    int run = part[t] - s;   // exclusive base
#pragma unroll
    for (int i = 0; i < C; ++i) {
        int idx = base + i;
        if (idx < N_NODES) buf[idx] = run;
        run += vals[i];
    }
}

__global__ void perm_kernel(const int* __restrict__ eidx, int* __restrict__ buf,
                            unsigned short* __restrict__ perm_lo,
                            unsigned char* __restrict__ perm_hi) {
    int e = blockIdx.x * blockDim.x + threadIdx.x;
    if (e < N_EDGES) {
        int pos = atomicAdd(&buf[eidx[e]], 1);
        perm_lo[pos] = (unsigned short)(e & 0xFFFF);
        perm_hi[pos] = (unsigned char)(e >> 16);
    }
}
// after perm: buf[n] = inclusive prefix -> count[n] = buf[n] - buf[n-1]

// ---- precompute P = nf@W1a, Q = nf@W1b (bf16) ----
__global__ __launch_bounds__(256, 4) void pq_kernel(
    const float* __restrict__ nf, const unsigned short* __restrict__ W1aT,
    const unsigned short* __restrict__ W1bT,
    unsigned short* __restrict__ P, unsigned short* __restrict__ Qm) {
    constexpr int SA = 136;
    __shared__ unsigned short sm[64 * SA];
    const int tid = threadIdx.x;
    const int n0 = blockIdx.x * 64;
    {
        const int m = tid >> 2, q = tid & 3;
        const int node = n0 + m;
        unsigned short* row = sm + m * SA + q * 32;
        if (node < N_NODES) {
            const float4* a4 = (const float4*)(nf + (size_t)node * HDIM) + q * 8;
#pragma unroll
            for (int j = 0; j < 8; ++j) {
                float4 v = a4[j];
                *(ushort4*)(row + 4 * j) = make_ushort4(f2bf(v.x), f2bf(v.y), f2bf(v.z), f2bf(v.w));
            }
        } else {
#pragma unroll
            for (int j = 0; j < 8; ++j) *(ushort4*)(row + 4 * j) = make_ushort4(0, 0, 0, 0);
        }
    }
    __syncthreads();

    const int wave = tid >> 6, lane = tid & 63;
    const int lr = lane & 15, kq = lane >> 4;
    f32x4 acca[8] = {}, accb[8] = {};
    const int arow = (wave * 16 + lr) * SA;
#pragma unroll
    for (int ks = 0; ks < 128; ks += 32) {
        bf16x8 a = *(const bf16x8*)(sm + arow + ks + kq * 8);
#pragma unroll
        for (int nt = 0; nt < 8; ++nt) {
            bf16x8 ba = *(const bf16x8*)(W1aT + (nt * 16 + lr) * 128 + ks + kq * 8);
            acca[nt] = __builtin_amdgcn_mfma_f32_16x16x32_bf16(a, ba, acca[nt], 0, 0, 0);
            bf16x8 bb = *(const bf16x8*)(W1bT + (nt * 16 + lr) * 128 + ks + kq * 8);
            accb[nt] = __builtin_amdgcn_mfma_f32_16x16x32_bf16(a, bb, accb[nt], 0, 0, 0);
        }
    }
#pragma unroll
    for (int nt = 0; nt < 8; ++nt) {
        const int col = nt * 16 + lr;
#pragma unroll
        for (int r = 0; r < 4; ++r) {
            const int node = n0 + wave * 16 + kq * 4 + r;
            if (node < N_NODES) {
                P[(size_t)node * HDIM + col] = f2bf(acca[nt][r]);
                Qm[(size_t)node * HDIM + col] = f2bf(accb[nt][r]);
            }
        }
    }
}

// ---- edge: e1 = silu(P[src]+Q[dst]+L[g]+fd@Wfd); layer2 MFMA; segmented scatter ----
__global__ __launch_bounds__(256, 4) void edge_kernel(
    const unsigned short* __restrict__ P, const unsigned short* __restrict__ Qm,
    const unsigned short* __restrict__ Lb, const float* __restrict__ frac_diff,
    const int* __restrict__ eidx, const int* __restrict__ e2g,
    const unsigned short* __restrict__ perm_lo, const unsigned char* __restrict__ perm_hi,
    const float* __restrict__ e_w1, const unsigned short* __restrict__ W2t,
    const float* __restrict__ b2, float* __restrict__ agg) {
    constexpr int S2 = 136;   // A2 bf16 row stride
    constexpr int SF = 132;   // fp32 staging row stride
    __shared__ float smf[64 * SF];          // 33792 B, unioned with A2 (needs 17408 B)
    __shared__ int ssrc[64];
    unsigned short* sm16 = (unsigned short*)smf;

    const int tid = threadIdx.x;
    const int e0 = blockIdx.x * 64;
    const int m = tid & 63;                 // edge row (wave-per-column-block mapping)
    const int i = e0 + m;
    const int e = (int)perm_lo[i] | ((int)perm_hi[i] << 16);
    const int src = eidx[e];
    const int dst = eidx[N_EDGES + e];
    const int g = e2g[e];
    const float fd0 = frac_diff[3 * e], fd1 = frac_diff[3 * e + 1], fd2 = frac_diff[3 * e + 2];
    if (tid < 64) ssrc[m] = src;

    // wave-uniform column block -> fd-weight loads are scalar/broadcast
    const int qw = __builtin_amdgcn_readfirstlane(tid >> 6);
    const int cb = qw * 32;
    const float* wr0 = e_w1 + 262 * HDIM + cb;
    const float* wr1 = wr0 + HDIM;
    const float* wr2 = wr1 + HDIM;
    const uint4* p4 = (const uint4*)(P + (size_t)src * HDIM + cb);
    const uint4* q4 = (const uint4*)(Qm + (size_t)dst * HDIM + cb);
    const uint4* l4 = (const uint4*)(Lb + (size_t)g * HDIM + cb);

    unsigned short* a2row = sm16 + m * S2 + cb;
#pragma unroll
    for (int jj = 0; jj < 4; ++jj) {
        uint4 pu = p4[jj], qu = q4[jj], lu = l4[jj];
        unsigned int outw[4];
        const unsigned int* pw = (const unsigned int*)&pu;
        const unsigned int* qq = (const unsigned int*)&qu;
        const unsigned int* lw = (const unsigned int*)&lu;
#pragma unroll
        for (int w = 0; w < 4; ++w) {
            const int c = jj * 8 + w * 2;
            float x0 = bflo(pw[w]) + bflo(qq[w]) + bflo(lw[w])
                     + fd0 * wr0[c] + fd1 * wr1[c] + fd2 * wr2[c];
            float x1 = bfhi(pw[w]) + bfhi(qq[w]) + bfhi(lw[w])
                     + fd0 * wr0[c + 1] + fd1 * wr1[c + 1] + fd2 * wr2[c + 1];
            outw[w] = (unsigned int)f2bf(silu_f(x0)) | ((unsigned int)f2bf(silu_f(x1)) << 16);
        }
        *(uint4*)(a2row + jj * 8) = *(uint4*)outw;
    }
    __syncthreads();

    // layer 2 (K=128)
    const int wave = tid >> 6, lane = tid & 63;
    const int lr = lane & 15, kq = lane >> 4;
    f32x4 acc2[8] = {};
    const int arow2 = (wave * 16 + lr) * S2;
#pragma unroll
    for (int ks = 0; ks < 128; ks += 32) {
        bf16x8 a = *(const bf16x8*)(sm16 + arow2 + ks + kq * 8);
#pragma unroll
        for (int nt = 0; nt < 8; ++nt) {
            bf16x8 bb = *(const bf16x8*)(W2t + (nt * 16 + lr) * 128 + ks + kq * 8);
            acc2[nt] = __builtin_amdgcn_mfma_f32_16x16x32_bf16(a, bb, acc2[nt], 0, 0, 0);
        }
    }
    __syncthreads();   // all reads of A2 done before fp32 overwrite

    // stage silu(layer2) fp32
#pragma unroll
    for (int nt = 0; nt < 8; ++nt) {
        const int col = nt * 16 + lr;
        const float bias = b2[col];
#pragma unroll
        for (int r = 0; r < 4; ++r) {
            const int mm = wave * 16 + kq * 4 + r;
            smf[mm * SF + col] = silu_f(acc2[nt][r] + bias);
        }
    }
    __syncthreads();

    // segmented reduction: thread = (col, half); walk 32 sorted rows
    {
        const int col = tid >> 1;
        const int r0 = (tid & 1) * 32;
        float sum = 0.0f;
        int cur = ssrc[r0];
#pragma unroll 1
        for (int r = r0; r < r0 + 32; ++r) {
            int s = ssrc[r];
            float v = smf[r * SF + col];
            if (s != cur) {
                atomicAdd(&agg[(size_t)cur * HDIM + col], sum);
                sum = 0.0f;
                cur = s;
            }
            sum += v;
        }
        atomicAdd(&agg[(size_t)cur * HDIM + col], sum);
    }
}

// ---- node MLP: h = concat(nf, agg/cnt) -> silu -> silu -> + nf (agg aliases out) ----
__global__ __launch_bounds__(256, 4) void node_kernel(
    const float* __restrict__ nf, const float* __restrict__ agg,
    const int* __restrict__ buf,
    const unsigned short* __restrict__ N1t, const float* __restrict__ b1,
    const unsigned short* __restrict__ N2t, const float* __restrict__ b2,
    float* __restrict__ out) {
    constexpr int SA = 264;
    constexpr int S2 = 136;
    __shared__ unsigned short sm[64 * SA];

    const int tid = threadIdx.x;
    const int n0 = blockIdx.x * 64;
    {
        const int m = tid >> 2, q = tid & 3;
        const int node = n0 + m;
        unsigned short* row = sm + m * SA;
        const int cbq = q * 32;
        if (node < N_NODES) {
            const int c = buf[node] - (node ? buf[node - 1] : 0);
            const float inv = 1.0f / (float)max(c, 1);
            const float4* a4 = (const float4*)(nf + (size_t)node * HDIM) + q * 8;
            const float4* g4 = (const float4*)(agg + (size_t)node * HDIM) + q * 8;
#pragma unroll
            for (int j = 0; j < 8; ++j) {
                float4 v = a4[j];
                *(ushort4*)(row + cbq + 4 * j) =
                    make_ushort4(f2bf(v.x), f2bf(v.y), f2bf(v.z), f2bf(v.w));
                float4 g = g4[j];
                *(ushort4*)(row + HDIM + cbq + 4 * j) =
                    make_ushort4(f2bf(g.x * inv), f2bf(g.y * inv), f2bf(g.z * inv), f2bf(g.w * inv));
            }
        } else {
#pragma unroll
            for (int j = 0; j < 8; ++j) {
                *(ushort4*)(row + cbq + 4 * j) = make_ushort4(0, 0, 0, 0);
                *(ushort4*)(row + HDIM + cbq + 4 * j) = make_ushort4(0, 0, 0, 0);
            }
        }
    }
    __syncthreads();

    const int wave = tid >> 6, lane = tid & 63;
    const int lr = lane & 15, kq = lane >> 4;

    f32x4 acc[8] = {};
    const int arow = (wave * 16 + lr) * SA;
#pragma unroll
    for (int ks = 0; ks < 256; ks += 32) {
        bf16x8 a = *(const bf16x8*)(sm + arow + ks + kq * 8);
#pragma unroll
        for (int nt = 0; nt < 8; ++nt) {
            bf16x8 bb = *(const bf16x8*)(N1t + (nt * 16 + lr) * 256 + ks + kq * 8);
            acc[nt] = __builtin_amdgcn_mfma_f32_16x16x32_bf16(a, bb, acc[nt], 0, 0, 0);
        }
    }
    __syncthreads();

#pragma unroll
    for (int nt = 0; nt < 8; ++nt) {
        const int col = nt * 16 + lr;
        const float bias = b1[col];
#pragma unroll
        for (int r = 0; r < 4; ++r) {
            const int mm = wave * 16 + kq * 4 + r;
            sm[mm * S2 + col] = f2bf(silu_f(acc[nt][r] + bias));
        }
    }
    __syncthreads();

    f32x4 acc2[8] = {};
    const int arow2 = (wave * 16 + lr) * S2;
#pragma unroll
    for (int ks = 0; ks < 128; ks += 32) {
        bf16x8 a = *(const bf16x8*)(sm + arow2 + ks + kq * 8);
#pragma unroll
        for (int nt = 0; nt < 8; ++nt) {
            bf16x8 bb = *(const bf16x8*)(N2t + (nt * 16 + lr) * 128 + ks + kq * 8);
            acc2[nt] = __builtin_amdgcn_mfma_f32_16x16x32_bf16(a, bb, acc2[nt], 0, 0, 0);
        }
    }

#pragma unroll
    for (int nt = 0; nt < 8; ++nt) {
        const int col = nt * 16 + lr;
        const float bias = b2[col];
#pragma unroll
        for (int r = 0; r < 4; ++r) {
            const int node = n0 + wave * 16 + kq * 4 + r;
            if (node < N_NODES) {
                const size_t o = (size_t)node * HDIM + col;
                out[o] = nf[o] + silu_f(acc2[nt][r] + bias);
            }
        }
    }
}

extern "C" void kernel_launch(void* const* d_in, const int* in_sizes, int n_in,
                              void* d_out, int out_size, void* d_ws, size_t ws_size,
                              hipStream_t stream) {
    const float* node_features = (const float*)d_in[0];
    const float* lattices = (const float*)d_in[2];
    const float* frac_diff = (const float*)d_in[3];
    const int* edge_index = (const int*)d_in[4];
    const int* edge2graph = (const int*)d_in[5];
    const float* e_w1 = (const float*)d_in[6];
    const float* e_b1 = (const float*)d_in[7];
    const float* e_w2 = (const float*)d_in[8];
    const float* e_b2 = (const float*)d_in[9];
    const float* n_w1 = (const float*)d_in[10];
    const float* n_b1 = (const float*)d_in[11];
    const float* n_w2 = (const float*)d_in[12];
    const float* n_b2 = (const float*)d_in[13];

    // workspace layout (bytes), total 28,920,896:
    //   0         W1aT 32768 | 32768 W1bT | 65536 W2t | 98304 N1t 65536 | 163840 N2t
    //   196608    Lb   (G*128 bf16, 524288)
    //   720896    P    (N*128 bf16, 12.8MB)
    //   13520896  Q    (N*128 bf16, 12.8MB)
    //   26320896  buf  (N int: hist -> offsets -> inclusive prefix)
    //   26520896  perm_lo (E u16) | 28120896 perm_hi (E u8)
    // agg lives in d_out (node_kernel reads rows before overwriting them).
    char* ws = (char*)d_ws;
    unsigned short* W1aT = (unsigned short*)(ws);
    unsigned short* W1bT = (unsigned short*)(ws + 32768);
    unsigned short* W2t  = (unsigned short*)(ws + 65536);
    unsigned short* N1t  = (unsigned short*)(ws + 98304);
    unsigned short* N2t  = (unsigned short*)(ws + 163840);
    unsigned short* Lb   = (unsigned short*)(ws + 196608);
    unsigned short* P    = (unsigned short*)(ws + 720896);
    unsigned short* Qm   = (unsigned short*)(ws + 13520896);
    int* buf             = (int*)(ws + 26320896);
    unsigned short* perm_lo = (unsigned short*)(ws + 26520896);
    unsigned char* perm_hi  = (unsigned char*)(ws + 28120896);
    float* agg = (float*)d_out;

    hipMemsetAsync(d_out, 0, (size_t)N_NODES * HDIM * 4, stream);
    hipMemsetAsync(buf, 0, (size_t)N_NODES * 4, stream);

    prep_kernel<<<1408, 256, 0, stream>>>(e_w1, e_w2, n_w1, n_w2, e_b1, lattices,
                                          W1aT, W1bT, W2t, N1t, N2t, Lb);
    hist_kernel<<<(N_EDGES + 255) / 256, 256, 0, stream>>>(edge_index, buf);
    scan_kernel<<<1, 1024, 0, stream>>>(buf);
    perm_kernel<<<(N_EDGES + 255) / 256, 256, 0, stream>>>(edge_index, buf, perm_lo, perm_hi);
    pq_kernel<<<(N_NODES + 63) / 64, 256, 0, stream>>>(node_features, W1aT, W1bT, P, Qm);

    edge_kernel<<<N_EDGES / 64, 256, 0, stream>>>(
        P, Qm, Lb, frac_diff, edge_index, edge2graph, perm_lo, perm_hi,
        e_w1, W2t, e_b2, agg);

    node_kernel<<<(N_NODES + 63) / 64, 256, 0, stream>>>(
        node_features, agg, buf, N1t, n_b1, N2t, n_b2, (float*)d_out);
}

// Round 4
// 632.164 us; speedup vs baseline: 1.3370x; 1.0191x over previous
//
#include <hip/hip_runtime.h>

#define N_NODES 50000
#define N_EDGES 800000
#define HDIM 128
#define N_GRAPH 2048

typedef __bf16 bf16x8 __attribute__((ext_vector_type(8)));
typedef float f32x4 __attribute__((ext_vector_type(4)));

// round-to-nearest-even fp32 -> bf16
static __device__ __forceinline__ unsigned short f2bf(float f) {
    unsigned int u = __float_as_uint(f);
    u += 0x7fffu + ((u >> 16) & 1u);
    return (unsigned short)(u >> 16);
}
static __device__ __forceinline__ float bflo(unsigned int u) { return __uint_as_float(u << 16); }
static __device__ __forceinline__ float bfhi(unsigned int u) { return __uint_as_float(u & 0xFFFF0000u); }
static __device__ __forceinline__ float bf2f(unsigned short v) { return __uint_as_float((unsigned int)v << 16); }

static __device__ __forceinline__ float silu_f(float x) {
    return x / (1.0f + __expf(-x));
}

// ---- one-shot prep: transposed bf16 weights + per-graph L = b1 + lat@W1c ----
__global__ void prep_kernel(const float* __restrict__ ew1, const float* __restrict__ ew2,
                            const float* __restrict__ nw1, const float* __restrict__ nw2,
                            const float* __restrict__ eb1, const float* __restrict__ lattices,
                            unsigned short* __restrict__ W1aT, unsigned short* __restrict__ W1bT,
                            unsigned short* __restrict__ W2t, unsigned short* __restrict__ N1t,
                            unsigned short* __restrict__ N2t, unsigned short* __restrict__ Lb) {
    int i = blockIdx.x * blockDim.x + threadIdx.x;
    if (i < 16384) {
        int n = i >> 7, k = i & 127;
        W1aT[i] = f2bf(ew1[k * 128 + n]);
    } else if (i < 32768) {
        int j = i - 16384; int n = j >> 7, k = j & 127;
        W1bT[j] = f2bf(ew1[(128 + k) * 128 + n]);
    } else if (i < 49152) {
        int j = i - 32768; int n = j >> 7, k = j & 127;
        W2t[j] = f2bf(ew2[k * 128 + n]);
    } else if (i < 81920) {
        int j = i - 49152; int n = j >> 8, k = j & 255;
        N1t[j] = f2bf(nw1[k * 128 + n]);
    } else if (i < 98304) {
        int j = i - 81920; int n = j >> 7, k = j & 127;
        N2t[j] = f2bf(nw2[k * 128 + n]);
    } else if (i < 98304 + 262144) {
        int j = i - 98304; int g = j >> 7, c = j & 127;
        float s = eb1[c];
#pragma unroll
        for (int t = 0; t < 6; ++t) s += lattices[g * 6 + t] * ew1[(256 + t) * 128 + c];
        Lb[j] = f2bf(s);
    }
}

// ---- sort by src: hist -> in-place scan -> bucket scatter (perm split u16/u8) ----
__global__ void hist_kernel(const int* __restrict__ eidx, int* __restrict__ buf) {
    int e = blockIdx.x * blockDim.x + threadIdx.x;
    if (e < N_EDGES) atomicAdd(&buf[eidx[e]], 1);
}

// single-block scan, LDS-chunked so all global traffic is coalesced
__global__ __launch_bounds__(1024) void scan_kernel(int* __restrict__ buf) {
    constexpr int CH = 12288;   // ints per chunk (12 per thread)
    __shared__ int lds[CH];
    __shared__ int part[1024];
    __shared__ int carry_s;
    const int t = threadIdx.x;
    if (t == 0) carry_s = 0;
    __syncthreads();
#pragma unroll 1
    for (int base = 0; base < N_NODES; base += CH) {
#pragma unroll
        for (int k = 0; k < CH / 1024; ++k) {
            int f = k * 1024 + t;
            lds[f] = (base + f < N_NODES) ? buf[base + f] : 0;
        }
        __syncthreads();
        int loc[12];
        int s = 0;
#pragma unroll
        for (int i = 0; i < 12; ++i) { loc[i] = lds[t * 12 + i]; s += loc[i]; }
        part[t] = s;
        __syncthreads();
        for (int off = 1; off < 1024; off <<= 1) {
            int tmp = (t >= off) ? part[t - off] : 0;
            __syncthreads();
            part[t] += tmp;
            __syncthreads();
        }
        const int total = part[1023];
        int run = carry_s + part[t] - s;   // exclusive base for this thread's chunk
#pragma unroll
        for (int i = 0; i < 12; ++i) { int tmp = loc[i]; lds[t * 12 + i] = run; run += tmp; }
        __syncthreads();
#pragma unroll
        for (int k = 0; k < CH / 1024; ++k) {
            int f = k * 1024 + t;
            if (base + f < N_NODES) buf[base + f] = lds[f];
        }
        __syncthreads();
        if (t == 0) carry_s += total;
        __syncthreads();
    }
}

__global__ void perm_kernel(const int* __restrict__ eidx, int* __restrict__ buf,
                            unsigned short* __restrict__ perm_lo,
                            unsigned char* __restrict__ perm_hi) {
    int e = blockIdx.x * blockDim.x + threadIdx.x;
    if (e < N_EDGES) {
        int pos = atomicAdd(&buf[eidx[e]], 1);
        perm_lo[pos] = (unsigned short)(e & 0xFFFF);
        perm_hi[pos] = (unsigned char)(e >> 16);
    }
}
// after perm: buf[n] = inclusive prefix -> count[n] = buf[n] - buf[n-1]

// ---- precompute P = nf@W1a, Q = nf@W1b (bf16), coalesced staged stores ----
__global__ __launch_bounds__(256, 4) void pq_kernel(
    const float* __restrict__ nf, const unsigned short* __restrict__ W1aT,
    const unsigned short* __restrict__ W1bT,
    unsigned short* __restrict__ P, unsigned short* __restrict__ Qm) {
    constexpr int SA = 136;
    __shared__ unsigned short sm[64 * SA];
    const int tid = threadIdx.x;
    const int n0 = blockIdx.x * 64;
    const int mrow = tid >> 2, q = tid & 3;
    {
        const int node = n0 + mrow;
        unsigned short* row = sm + mrow * SA + q * 32;
        if (node < N_NODES) {
            const float4* a4 = (const float4*)(nf + (size_t)node * HDIM) + q * 8;
#pragma unroll
            for (int j = 0; j < 8; ++j) {
                float4 v = a4[j];
                *(ushort4*)(row + 4 * j) = make_ushort4(f2bf(v.x), f2bf(v.y), f2bf(v.z), f2bf(v.w));
            }
        } else {
#pragma unroll
            for (int j = 0; j < 8; ++j) *(ushort4*)(row + 4 * j) = make_ushort4(0, 0, 0, 0);
        }
    }
    __syncthreads();

    const int wave = tid >> 6, lane = tid & 63;
    const int lr = lane & 15, kq = lane >> 4;
    f32x4 acca[8] = {}, accb[8] = {};
    const int arow = (wave * 16 + lr) * SA;
#pragma unroll
    for (int ks = 0; ks < 128; ks += 32) {
        bf16x8 a = *(const bf16x8*)(sm + arow + ks + kq * 8);
#pragma unroll
        for (int nt = 0; nt < 8; ++nt) {
            bf16x8 ba = *(const bf16x8*)(W1aT + (nt * 16 + lr) * 128 + ks + kq * 8);
            acca[nt] = __builtin_amdgcn_mfma_f32_16x16x32_bf16(a, ba, acca[nt], 0, 0, 0);
            bf16x8 bb = *(const bf16x8*)(W1bT + (nt * 16 + lr) * 128 + ks + kq * 8);
            accb[nt] = __builtin_amdgcn_mfma_f32_16x16x32_bf16(a, bb, accb[nt], 0, 0, 0);
        }
    }
    __syncthreads();

    const int node = n0 + mrow;
    // stage + write P
#pragma unroll
    for (int nt = 0; nt < 8; ++nt) {
        const int col = nt * 16 + lr;
#pragma unroll
        for (int r = 0; r < 4; ++r)
            sm[(wave * 16 + kq * 4 + r) * SA + col] = f2bf(acca[nt][r]);
    }
    __syncthreads();
    if (node < N_NODES) {
        uint4* dst = (uint4*)(P + (size_t)node * HDIM + q * 32);
        const uint4* srcp = (const uint4*)(sm + mrow * SA + q * 32);
#pragma unroll
        for (int j = 0; j < 4; ++j) dst[j] = srcp[j];
    }
    __syncthreads();
    // stage + write Q
#pragma unroll
    for (int nt = 0; nt < 8; ++nt) {
        const int col = nt * 16 + lr;
#pragma unroll
        for (int r = 0; r < 4; ++r)
            sm[(wave * 16 + kq * 4 + r) * SA + col] = f2bf(accb[nt][r]);
    }
    __syncthreads();
    if (node < N_NODES) {
        uint4* dst = (uint4*)(Qm + (size_t)node * HDIM + q * 32);
        const uint4* srcp = (const uint4*)(sm + mrow * SA + q * 32);
#pragma unroll
        for (int j = 0; j < 4; ++j) dst[j] = srcp[j];
    }
}

// ---- edge: e1 = silu(P[src]+Q[dst]+L[g]+fd@Wfd); layer2 MFMA; segmented scatter ----
__global__ __launch_bounds__(256, 6) void edge_kernel(
    const unsigned short* __restrict__ P, const unsigned short* __restrict__ Qm,
    const unsigned short* __restrict__ Lb, const float* __restrict__ frac_diff,
    const int* __restrict__ eidx, const int* __restrict__ e2g,
    const unsigned short* __restrict__ perm_lo, const unsigned char* __restrict__ perm_hi,
    const float* __restrict__ e_w1, const unsigned short* __restrict__ W2t,
    const float* __restrict__ b2, float* __restrict__ agg) {
    constexpr int S2 = 136;   // A2 bf16 row stride (16B-aligned rows)
    constexpr int SS = 132;   // bf16 stage row stride (conflict-free walk)
    __shared__ unsigned short sm16[64 * S2];   // 17408 B, union A2 / stage
    __shared__ int ssrc[64];
    __shared__ int sdst[64];
    __shared__ int sg[64];
    __shared__ float sfd[3 * 64];

    const int tid = threadIdx.x;
    const int e0 = blockIdx.x * 64;

    // metadata: load once per edge (not 4x)
    if (tid < 64) {
        const int i = e0 + tid;
        const int e = (int)perm_lo[i] | ((int)perm_hi[i] << 16);
        ssrc[tid] = eidx[e];
        sdst[tid] = eidx[N_EDGES + e];
        sg[tid] = e2g[e];
        sfd[tid] = frac_diff[3 * e];
        sfd[64 + tid] = frac_diff[3 * e + 1];
        sfd[128 + tid] = frac_diff[3 * e + 2];
    }
    __syncthreads();

    const int m = tid & 63;            // edge row
    const int qw = tid >> 6;           // column block (wave-uniform)
    const int cb = qw * 32;
    {
        const int src = ssrc[m], dst = sdst[m], g = sg[m];
        const float fd0 = sfd[m], fd1 = sfd[64 + m], fd2 = sfd[128 + m];
        const uint4* p4 = (const uint4*)(P + (size_t)src * HDIM + cb);
        const uint4* q4 = (const uint4*)(Qm + (size_t)dst * HDIM + cb);
        const uint4* l4 = (const uint4*)(Lb + (size_t)g * HDIM + cb);
        const float* wr = e_w1 + 262 * HDIM + cb;
        unsigned short* a2row = sm16 + m * S2 + cb;

        uint4 pu[4], qu[4], lu[4];
#pragma unroll
        for (int jj = 0; jj < 4; ++jj) { pu[jj] = p4[jj]; qu[jj] = q4[jj]; lu[jj] = l4[jj]; }
#pragma unroll
        for (int jj = 0; jj < 4; ++jj) {
            float w0[8], w1[8], w2[8];
            *(float4*)(w0) = *(const float4*)(wr + jj * 8);
            *(float4*)(w0 + 4) = *(const float4*)(wr + jj * 8 + 4);
            *(float4*)(w1) = *(const float4*)(wr + 128 + jj * 8);
            *(float4*)(w1 + 4) = *(const float4*)(wr + 128 + jj * 8 + 4);
            *(float4*)(w2) = *(const float4*)(wr + 256 + jj * 8);
            *(float4*)(w2 + 4) = *(const float4*)(wr + 256 + jj * 8 + 4);
            const unsigned int* pw = (const unsigned int*)&pu[jj];
            const unsigned int* qq = (const unsigned int*)&qu[jj];
            const unsigned int* lw = (const unsigned int*)&lu[jj];
            unsigned int outw[4];
#pragma unroll
            for (int w = 0; w < 4; ++w) {
                float x0 = bflo(pw[w]) + bflo(qq[w]) + bflo(lw[w])
                         + fd0 * w0[2 * w] + fd1 * w1[2 * w] + fd2 * w2[2 * w];
                float x1 = bfhi(pw[w]) + bfhi(qq[w]) + bfhi(lw[w])
                         + fd0 * w0[2 * w + 1] + fd1 * w1[2 * w + 1] + fd2 * w2[2 * w + 1];
                outw[w] = (unsigned int)f2bf(silu_f(x0)) | ((unsigned int)f2bf(silu_f(x1)) << 16);
            }
            *(uint4*)(a2row + jj * 8) = *(uint4*)outw;
        }
    }
    __syncthreads();

    // layer 2 (K=128)
    const int lane = tid & 63;
    const int lr = lane & 15, kq = lane >> 4;
    f32x4 acc2[8] = {};
    const int arow2 = (qw * 16 + lr) * S2;
#pragma unroll
    for (int ks = 0; ks < 128; ks += 32) {
        bf16x8 a = *(const bf16x8*)(sm16 + arow2 + ks + kq * 8);
#pragma unroll
        for (int nt = 0; nt < 8; ++nt) {
            bf16x8 bb = *(const bf16x8*)(W2t + (nt * 16 + lr) * 128 + ks + kq * 8);
            acc2[nt] = __builtin_amdgcn_mfma_f32_16x16x32_bf16(a, bb, acc2[nt], 0, 0, 0);
        }
    }
    __syncthreads();   // A2 reads done before stage overwrite

    // stage silu(layer2) bf16 (union with A2)
#pragma unroll
    for (int nt = 0; nt < 8; ++nt) {
        const int col = nt * 16 + lr;
        const float bias = b2[col];
#pragma unroll
        for (int r = 0; r < 4; ++r) {
            const int mm = qw * 16 + kq * 4 + r;
            sm16[mm * SS + col] = f2bf(silu_f(acc2[nt][r] + bias));
        }
    }
    __syncthreads();

    // segmented reduction: thread = (col, half); walk 32 sorted rows
    {
        const int col = tid >> 1;
        const int r0 = (tid & 1) * 32;
        float sum = 0.0f;
        int cur = ssrc[r0];
#pragma unroll 1
        for (int r = r0; r < r0 + 32; ++r) {
            int s = ssrc[r];
            float v = bf2f(sm16[r * SS + col]);
            if (s != cur) {
                atomicAdd(&agg[(size_t)cur * HDIM + col], sum);
                sum = 0.0f;
                cur = s;
            }
            sum += v;
        }
        atomicAdd(&agg[(size_t)cur * HDIM + col], sum);
    }
}

// ---- node MLP: h = concat(nf, agg/cnt) -> silu -> silu -> + nf (agg aliases out) ----
__global__ __launch_bounds__(256, 4) void node_kernel(
    const float* __restrict__ nf, const float* __restrict__ agg,
    const int* __restrict__ buf,
    const unsigned short* __restrict__ N1t, const float* __restrict__ b1,
    const unsigned short* __restrict__ N2t, const float* __restrict__ b2,
    float* __restrict__ out) {
    constexpr int SA = 264;
    constexpr int S2 = 136;
    constexpr int SFo = 132;   // fp32 out-stage stride (528 B rows, 16B-aligned)
    __shared__ unsigned short sm[64 * SA];   // 33792 B; reused as float[64][132]
    float* smf = (float*)sm;

    const int tid = threadIdx.x;
    const int n0 = blockIdx.x * 64;
    const int mrow = tid >> 2, q = tid & 3;
    {
        const int node = n0 + mrow;
        unsigned short* row = sm + mrow * SA;
        const int cbq = q * 32;
        if (node < N_NODES) {
            const int c = buf[node] - (node ? buf[node - 1] : 0);
            const float inv = 1.0f / (float)max(c, 1);
            const float4* a4 = (const float4*)(nf + (size_t)node * HDIM) + q * 8;
            const float4* g4 = (const float4*)(agg + (size_t)node * HDIM) + q * 8;
#pragma unroll
            for (int j = 0; j < 8; ++j) {
                float4 v = a4[j];
                *(ushort4*)(row + cbq + 4 * j) =
                    make_ushort4(f2bf(v.x), f2bf(v.y), f2bf(v.z), f2bf(v.w));
                float4 g = g4[j];
                *(ushort4*)(row + HDIM + cbq + 4 * j) =
                    make_ushort4(f2bf(g.x * inv), f2bf(g.y * inv), f2bf(g.z * inv), f2bf(g.w * inv));
            }
        } else {
#pragma unroll
            for (int j = 0; j < 8; ++j) {
                *(ushort4*)(row + cbq + 4 * j) = make_ushort4(0, 0, 0, 0);
                *(ushort4*)(row + HDIM + cbq + 4 * j) = make_ushort4(0, 0, 0, 0);
            }
        }
    }
    __syncthreads();

    const int wave = tid >> 6, lane = tid & 63;
    const int lr = lane & 15, kq = lane >> 4;

    f32x4 acc[8] = {};
    const int arow = (wave * 16 + lr) * SA;
#pragma unroll
    for (int ks = 0; ks < 256; ks += 32) {
        bf16x8 a = *(const bf16x8*)(sm + arow + ks + kq * 8);
#pragma unroll
        for (int nt = 0; nt < 8; ++nt) {
            bf16x8 bb = *(const bf16x8*)(N1t + (nt * 16 + lr) * 256 + ks + kq * 8);
            acc[nt] = __builtin_amdgcn_mfma_f32_16x16x32_bf16(a, bb, acc[nt], 0, 0, 0);
        }
    }
    __syncthreads();

#pragma unroll
    for (int nt = 0; nt < 8; ++nt) {
        const int col = nt * 16 + lr;
        const float bias = b1[col];
#pragma unroll
        for (int r = 0; r < 4; ++r) {
            const int mm = wave * 16 + kq * 4 + r;
            sm[mm * S2 + col] = f2bf(silu_f(acc[nt][r] + bias));
        }
    }
    __syncthreads();

    f32x4 acc2[8] = {};
    const int arow2 = (wave * 16 + lr) * S2;
#pragma unroll
    for (int ks = 0; ks < 128; ks += 32) {
        bf16x8 a = *(const bf16x8*)(sm + arow2 + ks + kq * 8);
#pragma unroll
        for (int nt = 0; nt < 8; ++nt) {
            bf16x8 bb = *(const bf16x8*)(N2t + (nt * 16 + lr) * 128 + ks + kq * 8);
            acc2[nt] = __builtin_amdgcn_mfma_f32_16x16x32_bf16(a, bb, acc2[nt], 0, 0, 0);
        }
    }
    __syncthreads();   // e-buffer reads done before fp32 stage overwrite

    // stage silu(layer2) fp32, then coalesced residual + store
#pragma unroll
    for (int nt = 0; nt < 8; ++nt) {
        const int col = nt * 16 + lr;
        const float bias = b2[col];
#pragma unroll
        for (int r = 0; r < 4; ++r) {
            const int mm = wave * 16 + kq * 4 + r;
            smf[mm * SFo + col] = silu_f(acc2[nt][r] + bias);
        }
    }
    __syncthreads();
    {
        const int node = n0 + mrow;
        if (node < N_NODES) {
            const float4* nfr = (const float4*)(nf + (size_t)node * HDIM) + q * 8;
            float4* outr = (float4*)(out + (size_t)node * HDIM) + q * 8;
            const float* st = smf + mrow * SFo + q * 32;
#pragma unroll
            for (int j = 0; j < 8; ++j) {
                float4 v = nfr[j];
                float4 s4 = *(const float4*)(st + 4 * j);
                v.x += s4.x; v.y += s4.y; v.z += s4.z; v.w += s4.w;
                outr[j] = v;
            }
        }
    }
}

extern "C" void kernel_launch(void* const* d_in, const int* in_sizes, int n_in,
                              void* d_out, int out_size, void* d_ws, size_t ws_size,
                              hipStream_t stream) {
    const float* node_features = (const float*)d_in[0];
    const float* lattices = (const float*)d_in[2];
    const float* frac_diff = (const float*)d_in[3];
    const int* edge_index = (const int*)d_in[4];
    const int* edge2graph = (const int*)d_in[5];
    const float* e_w1 = (const float*)d_in[6];
    const float* e_b1 = (const float*)d_in[7];
    const float* e_w2 = (const float*)d_in[8];
    const float* e_b2 = (const float*)d_in[9];
    const float* n_w1 = (const float*)d_in[10];
    const float* n_b1 = (const float*)d_in[11];
    const float* n_w2 = (const float*)d_in[12];
    const float* n_b2 = (const float*)d_in[13];

    // workspace layout (bytes), total 28,920,896 (same as R3-proven):
    //   0         W1aT | 32768 W1bT | 65536 W2t | 98304 N1t | 163840 N2t
    //   196608    Lb   (G*128 bf16)
    //   720896    P    (N*128 bf16, 12.8MB)
    //   13520896  Q    (N*128 bf16, 12.8MB)
    //   26320896  buf  (N int: hist -> offsets -> inclusive prefix)
    //   26520896  perm_lo (E u16) | 28120896 perm_hi (E u8)
    // agg lives in d_out (node_kernel reads its own rows before overwriting).
    char* ws = (char*)d_ws;
    unsigned short* W1aT = (unsigned short*)(ws);
    unsigned short* W1bT = (unsigned short*)(ws + 32768);
    unsigned short* W2t  = (unsigned short*)(ws + 65536);
    unsigned short* N1t  = (unsigned short*)(ws + 98304);
    unsigned short* N2t  = (unsigned short*)(ws + 163840);
    unsigned short* Lb   = (unsigned short*)(ws + 196608);
    unsigned short* P    = (unsigned short*)(ws + 720896);
    unsigned short* Qm   = (unsigned short*)(ws + 13520896);
    int* buf             = (int*)(ws + 26320896);
    unsigned short* perm_lo = (unsigned short*)(ws + 26520896);
    unsigned char* perm_hi  = (unsigned char*)(ws + 28120896);
    float* agg = (float*)d_out;

    hipMemsetAsync(d_out, 0, (size_t)N_NODES * HDIM * 4, stream);
    hipMemsetAsync(buf, 0, (size_t)N_NODES * 4, stream);

    prep_kernel<<<1408, 256, 0, stream>>>(e_w1, e_w2, n_w1, n_w2, e_b1, lattices,
                                          W1aT, W1bT, W2t, N1t, N2t, Lb);
    hist_kernel<<<(N_EDGES + 255) / 256, 256, 0, stream>>>(edge_index, buf);
    scan_kernel<<<1, 1024, 0, stream>>>(buf);
    perm_kernel<<<(N_EDGES + 255) / 256, 256, 0, stream>>>(edge_index, buf, perm_lo, perm_hi);
    pq_kernel<<<(N_NODES + 63) / 64, 256, 0, stream>>>(node_features, W1aT, W1bT, P, Qm);

    edge_kernel<<<N_EDGES / 64, 256, 0, stream>>>(
        P, Qm, Lb, frac_diff, edge_index, edge2graph, perm_lo, perm_hi,
        e_w1, W2t, e_b2, agg);

    node_kernel<<<(N_NODES + 63) / 64, 256, 0, stream>>>(
        node_features, agg, buf, N1t, n_b1, N2t, n_b2, (float*)d_out);
}